// Round 1
// 803.139 us; speedup vs baseline: 2.6921x; 2.6921x over previous
//
#include <hip/hip_runtime.h>
#include <hip/hip_bf16.h>

typedef unsigned short u16;
typedef unsigned int u32;
typedef __bf16 bf16x8 __attribute__((ext_vector_type(8)));
typedef float f32x4 __attribute__((ext_vector_type(4)));

__device__ __forceinline__ float bf2f(u16 h) { return __uint_as_float(((u32)h) << 16); }
__device__ __forceinline__ u16 f2bf(float f) {
    u32 u = __float_as_uint(f);
    u32 r = u + 0x7FFFu + ((u >> 16) & 1u);   // round-to-nearest-even
    return (u16)(r >> 16);
}
// monotone float->uint map for atomic max; key 0 is reserved "empty" (decodes from no writes -> 0.0)
__device__ __forceinline__ u32 fkey(float f) {
    u32 u = __float_as_uint(f);
    return ((int)u < 0) ? ~u : (u | 0x80000000u);
}
__device__ __forceinline__ float fdec(u32 k) {
    u32 u = (k & 0x80000000u) ? (k & 0x7FFFFFFFu) : ~k;
    return __uint_as_float(u);
}
__device__ __forceinline__ void unpack8(const u16* p, float* b) {
    uint4 v = *(const uint4*)p;
    b[0] = bf2f((u16)(v.x & 0xFFFF)); b[1] = bf2f((u16)(v.x >> 16));
    b[2] = bf2f((u16)(v.y & 0xFFFF)); b[3] = bf2f((u16)(v.y >> 16));
    b[4] = bf2f((u16)(v.z & 0xFFFF)); b[5] = bf2f((u16)(v.z >> 16));
    b[6] = bf2f((u16)(v.w & 0xFFFF)); b[7] = bf2f((u16)(v.w >> 16));
}
template<int BF16>
__device__ __forceinline__ float LD(const void* p, long i) {
    if constexpr (BF16) return bf2f(((const u16*)p)[i]);
    else return ((const float*)p)[i];
}
template<int BF16>
__device__ __forceinline__ void ld8w(const void* w, long off, float* b) {
    if constexpr (BF16) {
        unpack8((const u16*)w + off, b);
    } else {
        const float4* p = (const float4*)((const float*)w + off);
        float4 v0 = p[0], v1 = p[1];
        b[0] = v0.x; b[1] = v0.y; b[2] = v0.z; b[3] = v0.w;
        b[4] = v1.x; b[5] = v1.y; b[6] = v1.z; b[7] = v1.w;
    }
}

// -------- detector: flags[0]=1 if floats are bf16; flags[1]=1 if edge_index is int64 --------
__global__ void k_detect(const u32* __restrict__ x, const u32* __restrict__ ei, u32* __restrict__ flags) {
    if (threadIdx.x == 0 && blockIdx.x == 0) {
        int c = 0;
        for (int i = 0; i < 256; i++) {
            u32 e = (x[i] >> 7) & 0xFF;
            if (e >= 96 && e <= 160) c++;
        }
        flags[0] = (c >= 192) ? 1u : 0u;
        int z = 0;
        for (int i = 0; i < 64; i++) if (ei[2 * i + 1] == 0u) z++;
        flags[1] = (z >= 48) ? 1u : 0u;
    }
}

__global__ void k_init(u32* __restrict__ p, int n) {
    for (int i = blockIdx.x * blockDim.x + threadIdx.x; i < n; i += gridDim.x * blockDim.x)
        p[i] = 0u;
}

// -------- prep: transposed/padded bf16 weights.  w0t[c][kp] (128x128, kp<96 -> fw0 row kp+3),
// w1t[c][k] (96x128, pitch 128) --------
__global__ void k_prep(const void* __restrict__ fw0, const void* __restrict__ fw1,
                       u16* __restrict__ w0t, u16* __restrict__ w1t, const u32* __restrict__ flags) {
    int bf = (int)flags[0];
    int tid = blockIdx.x * blockDim.x + threadIdx.x;
    int stride = gridDim.x * blockDim.x;
    for (int i = tid; i < 128 * 128; i += stride) {
        int c = i >> 7, kp = i & 127;
        float v = 0.f;
        if (kp < 96) {
            int k = kp + 3;
            v = bf ? bf2f(((const u16*)fw0)[k * 128 + c]) : ((const float*)fw0)[k * 128 + c];
        }
        w0t[(long)c * 128 + kp] = f2bf(v);
    }
    for (int i = tid; i < 96 * 128; i += stride) {
        int c = i >> 7, k = i & 127;
        float v = bf ? bf2f(((const u16*)fw1)[k * 96 + c]) : ((const float*)fw1)[k * 96 + c];
        w1t[(long)c * 128 + k] = f2bf(v);
    }
}

// -------- counting sort of edges by dst: hist -> scan -> scatter --------
__global__ void k_hist(const u32* __restrict__ ei, u32* __restrict__ hist,
                       const u32* __restrict__ flags, int nE, int N) {
    u32 i64f = flags[1];
    for (long e = blockIdx.x * blockDim.x + threadIdx.x; e < nE; e += (long)gridDim.x * blockDim.x) {
        int dst = i64f ? (int)ei[2 * ((long)nE + e)] : (int)ei[(long)nE + e];
        dst = min(max(dst, 0), N - 1);
        atomicAdd(&hist[dst], 1u);
    }
}

__global__ void k_scan(u32* __restrict__ hist, int n) {   // 1 block, 256 threads, in-place exclusive scan
    __shared__ u32 sums[256];
    __shared__ u32 offs[256];
    int tid = threadIdx.x;
    int chunk = (n + 255) / 256;
    int lo = tid * chunk, hi = min(lo + chunk, n);
    u32 s = 0;
    for (int i = lo; i < hi; i++) s += hist[i];
    sums[tid] = s;
    __syncthreads();
    if (tid == 0) {
        u32 r = 0;
        for (int i = 0; i < 256; i++) { offs[i] = r; r += sums[i]; }
    }
    __syncthreads();
    u32 r = offs[tid];
    for (int i = lo; i < hi; i++) { u32 v = hist[i]; hist[i] = r; r += v; }
}

__global__ void k_scatter(const u32* __restrict__ ei, u32* __restrict__ cur,
                          u32* __restrict__ ssrc, u32* __restrict__ sdst,
                          const u32* __restrict__ flags, int nE, int N) {
    u32 i64f = flags[1];
    for (long e = blockIdx.x * blockDim.x + threadIdx.x; e < nE; e += (long)gridDim.x * blockDim.x) {
        int src, dst;
        if (i64f) { src = (int)ei[2 * e]; dst = (int)ei[2 * ((long)nE + e)]; }
        else      { src = (int)ei[e];     dst = (int)ei[(long)nE + e]; }
        src = min(max(src, 0), N - 1);
        dst = min(max(dst, 0), N - 1);
        u32 p = atomicAdd(&cur[dst], 1u);
        ssrc[p] = (u32)src;
        sdst[p] = (u32)dst;
    }
}

// -------- K1: delta = mlp_h(x)  (96 -> 64 relu -> 3), f32 out --------
template<int BF16>
__global__ void k_delta(const void* __restrict__ x,
                        const void* __restrict__ hw0, const void* __restrict__ hb0,
                        const void* __restrict__ hw1, const void* __restrict__ hb1,
                        float* __restrict__ delta, const u32* __restrict__ flags, int N)
{
    if (flags[0] != (u32)BF16) return;
    __shared__ float w0[96 * 64];
    __shared__ float b0[64];
    __shared__ float w1[64 * 3];
    __shared__ float b1[3];
    int tid = threadIdx.x;
    for (int i = tid; i < 96 * 64; i += 256) w0[i] = LD<BF16>(hw0, i);
    if (tid < 64) b0[tid] = LD<BF16>(hb0, tid);
    if (tid < 64 * 3) w1[tid] = LD<BF16>(hw1, tid);
    if (tid < 3) b1[tid] = LD<BF16>(hb1, tid);
    __syncthreads();
    int n = blockIdx.x * 256 + tid;
    if (n >= N) return;
    float acc[64];
#pragma unroll
    for (int j = 0; j < 64; j++) acc[j] = b0[j];
    if constexpr (BF16) {
        const u32* xr = (const u32*)x + (long)n * 48;
        for (int kk = 0; kk < 48; kk++) {
            u32 p = xr[kk];
            float a0 = bf2f((u16)(p & 0xFFFF));
            float a1 = bf2f((u16)(p >> 16));
            const float* wr0 = &w0[(2 * kk) * 64];
            const float* wr1 = &w0[(2 * kk + 1) * 64];
#pragma unroll
            for (int j = 0; j < 64; j++) acc[j] += a0 * wr0[j] + a1 * wr1[j];
        }
    } else {
        const float* xr = (const float*)x + (long)n * 96;
        for (int k = 0; k < 96; k++) {
            float a0 = xr[k];
            const float* wr = &w0[k * 64];
#pragma unroll
            for (int j = 0; j < 64; j++) acc[j] += a0 * wr[j];
        }
    }
    float d0 = b1[0], d1 = b1[1], d2 = b1[2];
#pragma unroll
    for (int j = 0; j < 64; j++) {
        float h = fmaxf(acc[j], 0.f);
        d0 += h * w1[j * 3 + 0];
        d1 += h * w1[j * 3 + 1];
        d2 += h * w1[j * 3 + 2];
    }
    delta[(long)n * 3 + 0] = d0; delta[(long)n * 3 + 1] = d1; delta[(long)n * 3 + 2] = d2;
}

// -------- K2: MFMA edge MLP over dst-sorted edges + run-reduced segment max --------
// 64 edges/tile, 4 waves; each wave owns 16 edge-rows (M=16) and all N-tiles.
// arena[0..16K):  ein  [64][128] bf16, swizzled (byte ^= (row&7)<<4), only k'=0..95 (= x feats) used
// arena[16K..32K): h   [64][128] bf16, same swizzle
// arena[0..32K):  out  [64][128] f32 via wave-local outOff mapping (overlays ein+h after GEMM2)
#define EB 64
__device__ __forceinline__ int outOff(int row, int col) {
    int j = row & 15, w2 = row >> 4;
    int base = (j < 8) ? (w2 * 4096 + j * 512) : (16384 + w2 * 4096 + (j - 8) * 512);
    return base + ((col ^ (((row >> 2) & 3) << 4)) << 2);
}

template<int BF16>
__global__ __launch_bounds__(256)
void k_edge(const void* __restrict__ x, const void* __restrict__ pos,
            const u32* __restrict__ ssrc, const u32* __restrict__ sdst,
            const float* __restrict__ delta,
            const u16* __restrict__ w0t, const u16* __restrict__ w1t,
            const void* __restrict__ fw0, const void* __restrict__ fb0, const void* __restrict__ fb1,
            const u32* __restrict__ flags, u32* __restrict__ aggKey, int nE, int N)
{
    if (flags[0] != (u32)BF16) return;
    __shared__ __align__(16) char arena[32768];
    __shared__ float relS[64][4];
    __shared__ int dstS[64];
    __shared__ float b0s[128];
    __shared__ float b1s[96];
    __shared__ float w0rS[3 * 128];
    int tid = threadIdx.x;
    if (tid < 128) b0s[tid] = LD<BF16>(fb0, tid);
    if (tid < 96)  b1s[tid] = LD<BF16>(fb1, tid);
    for (int i = tid; i < 384; i += 256) w0rS[i] = LD<BF16>(fw0, i);   // fw0 rows 0..2 (rel part), f32 in LDS
    __syncthreads();

    const int lane = tid & 63;
    const int wid  = tid >> 6;
    const int mrow0 = wid * 16;
    const int arow = mrow0 + (lane & 15);
    const int kgrp = lane >> 4;          // 0..3
    const int srow = tid >> 2;           // staging row 0..63 (wave-local: rows 16w..16w+15)
    const int q = tid & 3;

    float b0v[8];
#pragma unroll
    for (int nt = 0; nt < 8; nt++) b0v[nt] = b0s[nt * 16 + (lane & 15)];
    const int rcol = tid % 96;
    const float b1c = (tid < 192) ? b1s[rcol] : 0.f;

    int ntile = nE / EB;   // 12500 exact
    for (int t = blockIdx.x; t < ntile; t += gridDim.x) {
        asm volatile("" ::: "memory");   // block LICM from hoisting loop-invariant B-fragment loads
        // ---- stage 64 edges ----
        {
            long E = (long)t * EB + srow;
            u32 src = ssrc[E];
            if (q == 3) {
                u32 dst = sdst[E];
                dstS[srow] = (int)dst;
#pragma unroll
                for (int c = 0; c < 3; c++) {
                    relS[srow][c] = LD<BF16>(pos, (long)src * 3 + c) - LD<BF16>(pos, (long)dst * 3 + c)
                                  + delta[(long)dst * 3 + c];
                }
            } else {
                if constexpr (BF16) {
                    const uint4* xp = (const uint4*)((const u16*)x + (size_t)src * 96);
#pragma unroll
                    for (int j = 0; j < 4; j++) {
                        int c = q * 4 + j;
                        uint4 v = xp[c];
                        *(uint4*)(arena + srow * 256 + ((c * 16) ^ ((srow & 7) << 4))) = v;
                    }
                } else {
                    const float4* xp = (const float4*)((const float*)x + (size_t)src * 96);
#pragma unroll
                    for (int j = 0; j < 4; j++) {
                        int c = q * 4 + j;
                        float4 v0 = xp[2 * c], v1 = xp[2 * c + 1];
                        u32 o0 = (u32)f2bf(v0.x) | ((u32)f2bf(v0.y) << 16);
                        u32 o1 = (u32)f2bf(v0.z) | ((u32)f2bf(v0.w) << 16);
                        u32 o2 = (u32)f2bf(v1.x) | ((u32)f2bf(v1.y) << 16);
                        u32 o3 = (u32)f2bf(v1.z) | ((u32)f2bf(v1.w) << 16);
                        *(uint4*)(arena + srow * 256 + ((c * 16) ^ ((srow & 7) << 4))) = make_uint4(o0, o1, o2, o3);
                    }
                }
            }
        }
        __syncthreads();

        // ---- GEMM1: h = relu(ein @ W0 + b0), K=96 MFMA + rank-3 rel init in f32 ----
        float rl[4][3];
#pragma unroll
        for (int r = 0; r < 4; r++) {
            int row = mrow0 + kgrp * 4 + r;
            rl[r][0] = relS[row][0]; rl[r][1] = relS[row][1]; rl[r][2] = relS[row][2];
        }
        f32x4 acc[8];
#pragma unroll
        for (int nt = 0; nt < 8; nt++) {
            int col = nt * 16 + (lane & 15);
            float wr0 = w0rS[col], wr1 = w0rS[128 + col], wr2 = w0rS[256 + col];
#pragma unroll
            for (int r = 0; r < 4; r++)
                acc[nt][r] = rl[r][0] * wr0 + rl[r][1] * wr1 + rl[r][2] * wr2;
        }
        int sw = (arow & 7) << 4;
        bf16x8 a0 = *(const bf16x8*)(arena + arow * 256 + ((0   + kgrp * 16) ^ sw));
        bf16x8 a1 = *(const bf16x8*)(arena + arow * 256 + ((64  + kgrp * 16) ^ sw));
        bf16x8 a2 = *(const bf16x8*)(arena + arow * 256 + ((128 + kgrp * 16) ^ sw));
#pragma unroll
        for (int nt = 0; nt < 8; nt++) {
            const u16* wp = w0t + (long)(nt * 16 + (lane & 15)) * 128 + kgrp * 8;
            acc[nt] = __builtin_amdgcn_mfma_f32_16x16x32_bf16(a0, *(const bf16x8*)(wp),      acc[nt], 0, 0, 0);
            acc[nt] = __builtin_amdgcn_mfma_f32_16x16x32_bf16(a1, *(const bf16x8*)(wp + 32), acc[nt], 0, 0, 0);
            acc[nt] = __builtin_amdgcn_mfma_f32_16x16x32_bf16(a2, *(const bf16x8*)(wp + 64), acc[nt], 0, 0, 0);
        }
        // h -> bf16 -> LDS (wave-local rows; in-order DS per wave, no barrier needed)
#pragma unroll
        for (int nt = 0; nt < 8; nt++) {
            int col = nt * 16 + (lane & 15);
#pragma unroll
            for (int r = 0; r < 4; r++) {
                int row = mrow0 + kgrp * 4 + r;
                float hv = fmaxf(acc[nt][r] + b0v[nt], 0.f);
                *(u16*)(arena + 16384 + row * 256 + ((col * 2) ^ ((row & 7) << 4))) = f2bf(hv);
            }
        }
        // ---- GEMM2: e2 = h @ W1, K=128, N=96 ----
        bf16x8 h0 = *(const bf16x8*)(arena + 16384 + arow * 256 + ((0   + kgrp * 16) ^ sw));
        bf16x8 h1 = *(const bf16x8*)(arena + 16384 + arow * 256 + ((64  + kgrp * 16) ^ sw));
        bf16x8 h2 = *(const bf16x8*)(arena + 16384 + arow * 256 + ((128 + kgrp * 16) ^ sw));
        bf16x8 h3 = *(const bf16x8*)(arena + 16384 + arow * 256 + ((192 + kgrp * 16) ^ sw));
        f32x4 acc2[6];
#pragma unroll
        for (int nt = 0; nt < 6; nt++) {
#pragma unroll
            for (int r = 0; r < 4; r++) acc2[nt][r] = 0.f;
        }
#pragma unroll
        for (int nt = 0; nt < 6; nt++) {
            const u16* wp = w1t + (long)(nt * 16 + (lane & 15)) * 128 + kgrp * 8;
            acc2[nt] = __builtin_amdgcn_mfma_f32_16x16x32_bf16(h0, *(const bf16x8*)(wp),      acc2[nt], 0, 0, 0);
            acc2[nt] = __builtin_amdgcn_mfma_f32_16x16x32_bf16(h1, *(const bf16x8*)(wp + 32), acc2[nt], 0, 0, 0);
            acc2[nt] = __builtin_amdgcn_mfma_f32_16x16x32_bf16(h2, *(const bf16x8*)(wp + 64), acc2[nt], 0, 0, 0);
            acc2[nt] = __builtin_amdgcn_mfma_f32_16x16x32_bf16(h3, *(const bf16x8*)(wp + 96), acc2[nt], 0, 0, 0);
        }
        // out (f32) into wave-local arena slices
#pragma unroll
        for (int nt = 0; nt < 6; nt++) {
            int col = nt * 16 + (lane & 15);
#pragma unroll
            for (int r = 0; r < 4; r++) {
                int row = mrow0 + kgrp * 4 + r;
                *(float*)(arena + outOff(row, col)) = acc2[nt][r];
            }
        }
        __syncthreads();
        // ---- run-scan reduction + one atomic per (dst-run, col) ----
        if (tid < 192) {
            int half = tid / 96;
            int r0 = half * 32;
            int curd = dstS[r0];
            float m = -3.0e38f;
            for (int rr = 0; rr < 32; rr++) {
                int row = r0 + rr;
                float v = *(const float*)(arena + outOff(row, rcol));
                int d = dstS[row];
                if (d != curd) {
                    atomicMax(&aggKey[(size_t)curd * 96 + rcol], fkey(m + b1c));
                    curd = d; m = v;
                } else {
                    m = fmaxf(m, v);
                }
            }
            atomicMax(&aggKey[(size_t)curd * 96 + rcol], fkey(m + b1c));
        }
        __syncthreads();
    }
}

// -------- K3: out = x + mlp_g(agg)  (96 -> 128 relu -> 96) --------
template<int BF16>
__global__ void k_node(const void* __restrict__ x, const u32* __restrict__ aggKey,
                       const void* __restrict__ gw0, const void* __restrict__ gb0,
                       const void* __restrict__ gw1, const void* __restrict__ gb1,
                       void* __restrict__ out, const u32* __restrict__ flags, int N)
{
    if (flags[0] != (u32)BF16) return;
    __shared__ __align__(16) u16 w0[96 * 128];
    __shared__ float b0[128];
    __shared__ float b1[96];
    __shared__ float buf[16 * 132];
    int tid = threadIdx.x;
    if constexpr (BF16) {
        for (int i = tid; i < 96 * 128 / 2; i += 256) ((u32*)w0)[i] = ((const u32*)gw0)[i];
    } else {
        for (int i = tid; i < 96 * 128; i += 256) w0[i] = f2bf(((const float*)gw0)[i]);
    }
    if (tid < 128) b0[tid] = LD<BF16>(gb0, tid);
    if (tid < 96)  b1[tid] = LD<BF16>(gb1, tid);
    __syncthreads();

    int ntile = (N + 15) / 16;
    for (int t = blockIdx.x; t < ntile; t += gridDim.x) {
        {
            int nl = tid >> 4, g = tid & 15;
            int n = t * 16 + nl;
            if (n < N) {
                const u32* ar = aggKey + (size_t)n * 96 + g * 6;
#pragma unroll
                for (int q = 0; q < 6; q++) {
                    u32 k2 = ar[q];
                    buf[nl * 132 + g * 6 + q] = (k2 == 0u) ? 0.f : fdec(k2);
                }
            } else {
#pragma unroll
                for (int q = 0; q < 6; q++) buf[nl * 132 + g * 6 + q] = 0.f;
            }
        }
        __syncthreads();
        {
            int tx = tid & 15;
            int ty = tid >> 4;
            float acc[8];
#pragma unroll
            for (int c = 0; c < 8; c++) acc[c] = 0.f;
            const float* e0 = &buf[ty * 132];
            for (int k = 0; k < 96; k++) {
                float a0 = e0[k];
                float b[8];
                unpack8(&w0[k * 128 + tx * 8], b);
#pragma unroll
                for (int c = 0; c < 8; c++) acc[c] += a0 * b[c];
            }
            __syncthreads();
#pragma unroll
            for (int c = 0; c < 8; c++) {
                int col = tx * 8 + c;
                buf[ty * 132 + col] = fmaxf(acc[c] + b0[col], 0.f);
            }
        }
        __syncthreads();
        if (tid < 192) {
            int tx = tid % 12;
            int ty = tid / 12;
            float acc[8];
#pragma unroll
            for (int c = 0; c < 8; c++) acc[c] = 0.f;
            const float* h0 = &buf[ty * 132];
            for (int k = 0; k < 128; k++) {
                float a0 = h0[k];
                float b[8];
                ld8w<BF16>(gw1, (long)k * 96 + tx * 8, b);
#pragma unroll
                for (int c = 0; c < 8; c++) acc[c] += a0 * b[c];
            }
            int n = t * 16 + ty;
            if (n < N) {
                if constexpr (BF16) {
                    float xv[8];
                    unpack8((const u16*)x + (size_t)n * 96 + tx * 8, xv);
                    u32 o[4];
#pragma unroll
                    for (int c = 0; c < 4; c++) {
                        u16 lo = f2bf(xv[2 * c] + acc[2 * c] + b1[tx * 8 + 2 * c]);
                        u16 hi = f2bf(xv[2 * c + 1] + acc[2 * c + 1] + b1[tx * 8 + 2 * c + 1]);
                        o[c] = (u32)lo | ((u32)hi << 16);
                    }
                    *(uint4*)((u16*)out + (size_t)n * 96 + tx * 8) = make_uint4(o[0], o[1], o[2], o[3]);
                } else {
                    const float* xr = (const float*)x + (size_t)n * 96 + tx * 8;
                    float* orow = (float*)out + (size_t)n * 96 + tx * 8;
#pragma unroll
                    for (int c = 0; c < 8; c++) orow[c] = xr[c] + acc[c] + b1[tx * 8 + c];
                }
            }
        }
        __syncthreads();
    }
}

extern "C" void kernel_launch(void* const* d_in, const int* in_sizes, int n_in,
                              void* d_out, int out_size, void* d_ws, size_t ws_size,
                              hipStream_t stream) {
    const void* x   = d_in[0];
    const void* pos = d_in[1];
    const void* ei  = d_in[2];
    const void* hw0 = d_in[3];
    const void* hb0 = d_in[4];
    const void* hw1 = d_in[5];
    const void* hb1 = d_in[6];
    const void* fw0 = d_in[7];
    const void* fb0 = d_in[8];
    const void* fw1 = d_in[9];
    const void* fb1 = d_in[10];
    const void* gw0 = d_in[11];
    const void* gb0 = d_in[12];
    const void* gw1 = d_in[13];
    const void* gb1 = d_in[14];

    int N  = in_sizes[0] / 96;   // 50000
    int nE = in_sizes[2] / 2;    // 800000

    // workspace layout (all offsets 16B aligned), total ~26.5 MB
    u32*   flags  = (u32*)d_ws;                                 // 256 B
    float* delta  = (float*)((char*)d_ws + 256);                // 600,000 B
    u16*   w0t    = (u16*)((char*)d_ws + 600320);               // 32,768 B
    u16*   w1t    = (u16*)((char*)d_ws + 633088);               // 24,576 B
    u32*   binCur = (u32*)((char*)d_ws + 657664);               // 200,000 B (hist -> cursor)
    u32*   aggKey = (u32*)((char*)d_ws + 857856);               // 19,200,000 B
    u32*   ssrc   = (u32*)((char*)d_ws + 20057856);             // 3,200,000 B
    u32*   sdst   = (u32*)((char*)d_ws + 23257856);             // 3,200,000 B -> end 26,457,856

    k_detect<<<1, 64, 0, stream>>>((const u32*)x, (const u32*)ei, flags);
    k_init<<<1024, 256, 0, stream>>>(aggKey, N * 96);
    k_init<<<256, 256, 0, stream>>>(binCur, N);
    k_prep<<<64, 256, 0, stream>>>(fw0, fw1, w0t, w1t, flags);
    k_hist<<<1024, 256, 0, stream>>>((const u32*)ei, binCur, flags, nE, N);
    k_scan<<<1, 256, 0, stream>>>(binCur, N);
    k_scatter<<<1024, 256, 0, stream>>>((const u32*)ei, binCur, ssrc, sdst, flags, nE, N);
    k_delta<1><<<(N + 255) / 256, 256, 0, stream>>>(x, hw0, hb0, hw1, hb1, delta, flags, N);
    k_delta<0><<<(N + 255) / 256, 256, 0, stream>>>(x, hw0, hb0, hw1, hb1, delta, flags, N);
    k_edge<1><<<2048, 256, 0, stream>>>(x, pos, ssrc, sdst, delta, w0t, w1t, fw0, fb0, fb1, flags, aggKey, nE, N);
    k_edge<0><<<2048, 256, 0, stream>>>(x, pos, ssrc, sdst, delta, w0t, w1t, fw0, fb0, fb1, flags, aggKey, nE, N);
    k_node<1><<<960, 256, 0, stream>>>(x, aggKey, gw0, gb0, gw1, gb1, d_out, flags, N);
    k_node<0><<<960, 256, 0, stream>>>(x, aggKey, gw0, gb0, gw1, gb1, d_out, flags, N);
}